// Round 9
// baseline (693.435 us; speedup 1.0000x reference)
//
#include <hip/hip_runtime.h>
#include <hip/hip_cooperative_groups.h>
#include <hip/hip_bf16.h>
#include <math.h>

#define H 768
#define B 256
#define T 100

typedef __attribute__((ext_vector_type(8))) short short8;
typedef __attribute__((ext_vector_type(4))) float f32x4;
typedef __attribute__((ext_vector_type(4))) unsigned short us4;
typedef unsigned long long u64;

namespace cg = cooperative_groups;

static __device__ __forceinline__ float sigm(float x) {
    return 1.0f / (1.0f + __expf(-x));
}
static __device__ __forceinline__ float tanh_fast(float x) {
    return 1.0f - 2.0f / (__expf(2.0f * x) + 1.0f);
}
static __device__ __forceinline__ unsigned short bf16b(float x) {
    __hip_bfloat16 h = __float2bfloat16(x);
    return *(unsigned short*)&h;
}
// bf16(a+b) of 8 consecutive f32 from two arrays -> short8 (== old Wc prep op)
static __device__ __forceinline__ short8 cvt8sum(const float* pa, const float* pb) {
    f32x4 a0 = *(const f32x4*)pa, a1 = *(const f32x4*)(pa + 4);
    f32x4 b0 = *(const f32x4*)pb, b1 = *(const f32x4*)(pb + 4);
    short8 r;
#pragma unroll
    for (int e = 0; e < 4; ++e) {
        r[e]     = (short)bf16b(a0[e] + b0[e]);
        r[4 + e] = (short)bf16b(a1[e] + b1[e]);
    }
    return r;
}
// bf16 of 8 consecutive f32 -> short8 (== old Wcat prep op)
static __device__ __forceinline__ short8 cvt8(const float* p) {
    f32x4 a0 = *(const f32x4*)p, a1 = *(const f32x4*)(p + 4);
    short8 r;
#pragma unroll
    for (int e = 0; e < 4; ++e) {
        r[e]     = (short)bf16b(a0[e]);
        r[4 + e] = (short)bf16b(a1[e]);
    }
    return r;
}

// ---------------- persistent recurrence + in-kernel prep (cooperative) -------
// R24 core VERBATIM for the t-loop (proven 337us: sleepless poll, full
// __syncthreads at (D)). R25: prep dispatch ELIMINATED (gap ~35us was the
// largest non-lstm line item):
//  - Wc/Wcat/bias/A0 buffers are gone: weights pinned straight from fp32
//    Wih/Whh (same bf16(a+b) op -> bit-identical), t=0 weights streamed fp32
//    with inline cvt, [x0|h0] staged f32->bf16 directly to LDS, bias summed
//    per cell-thread. None of it crosses blocks -> no ordering needed.
//  - Wp converted in-kernel (read only by next dispatch -> kernel-end release).
//  - sig zeroing is the ONLY cross-block-ordered prep: agent-scope zero
//    stores + vmcnt(0) + grid.sync() (cooperative launch) before any publish.
// Refuted-by-counters (do not revisit): sc0/L2 exchange (R16); flag-gated
// exchange (R17); proj folded into tail (R18); (D)-drain removal + dual-acc
// MFMA (R22).
#define LDS_H_STRIDE  772    // shorts; 8B-aligned rows, low conflicts (R9-measured)
#define LDS_T0_STRIDE 1540   // shorts
#define XCH_STRIDE    17     // 16 + 1 pad floats

#define KSTEP(nm, idx) { \
    short8 a_ = *(const short8*)(&lds_h[col * LDS_H_STRIDE + (idx) * 32 + quad * 8]); \
    acc = __builtin_amdgcn_mfma_f32_16x16x32_bf16(a_, nm, acc, 0, 0, 0); }

static __device__ __forceinline__ bool sig_ok(u64 x) {
    return (unsigned short)x && (unsigned short)(x >> 16) &&
           (unsigned short)(x >> 32) && (unsigned short)(x >> 48);
}

__global__ __launch_bounds__(768, 3) void lstm_persist(
    const float* __restrict__ src,    // B x 16 x H fp32
    const float* __restrict__ h0f,    // B x H fp32
    const float* __restrict__ c0in,   // B x H fp32
    const float* __restrict__ Wih,    // 3072 x 768 fp32
    const float* __restrict__ Whh,    // 3072 x 768 fp32
    const float* __restrict__ bih,    // 3072 fp32
    const float* __restrict__ bhh,    // 3072 fp32
    const float* __restrict__ Wpost,  // 72 x 768 fp32
    __hip_bfloat16* __restrict__ Wp,  // 80 x 768 bf16 out (for proj)
    unsigned* sig)                    // T x B x 384 u32 (~bf16 pairs)
{
    const int mtg  = blockIdx.x >> 4;    // batch group 0..15 (16 batches)
    const int jg   = blockIdx.x & 15;    // j group 0..15 (48 j values)
    const int tid  = threadIdx.x;
    const int lane = tid & 63;
    const int wave = tid >> 6;           // 0..11
    const int col  = lane & 15;
    const int quad = lane >> 4;
    const int jt_l = wave >> 2;          // 0..2  local j-tile
    const int gate = wave & 3;           // 0..3  (i,f,g,o)
    const int j    = jg * 48 + jt_l * 16 + col;   // this wave's j column

    __shared__ short lds_h[16 * LDS_T0_STRIDE];   // 49280 B (t0 tile; t>=1 stride 772)
    __shared__ float xch[12 * 16 * XCH_STRIDE];   // 13056 B gate exchange

    // ---- prep 0a: zero my 153.6KB sig share (agent stores -> MALL) ----
    u64* myz = (u64*)sig + (size_t)blockIdx.x * 19200 + tid;
#pragma unroll
    for (int k = 0; k < 25; ++k)
        __hip_atomic_store(myz + (size_t)k * 768, 0ull,
                           __ATOMIC_RELAXED, __HIP_MEMORY_SCOPE_AGENT);

    // ---- prep 0b: Wp bf16 (blocks 0..79; consumed by NEXT dispatch only) ----
    if (blockIdx.x < 80 && tid < 192) {
        const int r = blockIdx.x, k4 = tid * 4;
        us4 w = (us4){0, 0, 0, 0};
        if (r < 72) {
            f32x4 v = *(const f32x4*)(Wpost + (size_t)r * H + k4);
#pragma unroll
            for (int e = 0; e < 4; ++e) w[e] = bf16b(v[e]);
        }
        *(us4*)((unsigned short*)Wp + (size_t)r * H + k4) = w;
    }

    // ---- prep 0c: pin Wc slice straight from fp32 (bf16(a+b), bit-identical) ----
    const float* wi = Wih + (size_t)(gate * H + j) * H + quad * 8;
    const float* wh = Whh + (size_t)(gate * H + j) * H + quad * 8;
    short8 w00 = cvt8sum(wi +   0, wh +   0), w01 = cvt8sum(wi +  32, wh +  32),
           w02 = cvt8sum(wi +  64, wh +  64), w03 = cvt8sum(wi +  96, wh +  96),
           w04 = cvt8sum(wi + 128, wh + 128), w05 = cvt8sum(wi + 160, wh + 160),
           w06 = cvt8sum(wi + 192, wh + 192), w07 = cvt8sum(wi + 224, wh + 224),
           w08 = cvt8sum(wi + 256, wh + 256), w09 = cvt8sum(wi + 288, wh + 288),
           w10 = cvt8sum(wi + 320, wh + 320), w11 = cvt8sum(wi + 352, wh + 352),
           w12 = cvt8sum(wi + 384, wh + 384), w13 = cvt8sum(wi + 416, wh + 416),
           w14 = cvt8sum(wi + 448, wh + 448), w15 = cvt8sum(wi + 480, wh + 480),
           w16 = cvt8sum(wi + 512, wh + 512), w17 = cvt8sum(wi + 544, wh + 544),
           w18 = cvt8sum(wi + 576, wh + 576), w19 = cvt8sum(wi + 608, wh + 608),
           w20 = cvt8sum(wi + 640, wh + 640), w21 = cvt8sum(wi + 672, wh + 672),
           w22 = cvt8sum(wi + 704, wh + 704), w23 = cvt8sum(wi + 736, wh + 736);

    // ---- prep 0d: stage [x0|h0] f32 -> bf16 -> LDS (t0 tile) ----
#pragma unroll
    for (int i = 0; i < 8; ++i) {
        int idx = tid + i * 768;          // 0..6143 (16 rows x 384 u64)
        int br  = idx / 384;
        int ch  = idx % 384;
        int cv  = ch * 4;                 // bf16 col 0..1535
        const float* pf = (cv < 768)
            ? src + ((size_t)(mtg * 16 + br) * 16 + 15) * H + cv       // src[:, -1]
            : h0f + (size_t)(mtg * 16 + br) * H + (cv - 768);
        f32x4 v = *(const f32x4*)pf;
        us4 u;
#pragma unroll
        for (int e = 0; e < 4; ++e) u[e] = bf16b(v[e]);
        *(us4*)&lds_h[br * LDS_T0_STRIDE + ch * 4] = u;
    }

    // ---- cell-role state (threads 0..383): c0 + bias from fp32 inputs ----
    const int p    = tid;                 // pair id if < 384 (waves 0..5)
    const int bb   = p / 24;              // local batch 0..15
    const int jp   = p % 24;
    const int jloc = jp * 2;              // local j 0..46 (even)
    const int cjt  = jloc >> 4;           // j-tile of the pair
    const int jcol = jloc & 15;
    const int bglob = mtg * 16 + bb;
    const int jglob = jg * 48 + jloc;
    float c0v = 0.f, c1v = 0.f;
    float bi0=0,bi1=0,bf0=0,bf1=0,bg0=0,bg1=0,bo0=0,bo1=0;
    if (p < 384) {
        c0v = c0in[(size_t)bglob * H + jglob];
        c1v = c0in[(size_t)bglob * H + jglob + 1];
        bi0 = bih[0*H + jglob]     + bhh[0*H + jglob];
        bi1 = bih[0*H + jglob + 1] + bhh[0*H + jglob + 1];
        bf0 = bih[1*H + jglob]     + bhh[1*H + jglob];
        bf1 = bih[1*H + jglob + 1] + bhh[1*H + jglob + 1];
        bg0 = bih[2*H + jglob]     + bhh[2*H + jglob];
        bg1 = bih[2*H + jglob + 1] + bhh[2*H + jglob + 1];
        bo0 = bih[3*H + jglob]     + bhh[3*H + jglob];
        bo1 = bih[3*H + jglob + 1] + bhh[3*H + jglob + 1];
    }

    // ---- grid barrier: all sig zeroes at the MALL before any publish ----
    asm volatile("s_waitcnt vmcnt(0)" ::: "memory");
    cg::this_grid().sync();

    const u64* sig64c = (const u64*)sig;
    const int r0  = tid / 192;    // staging row base 0..3
    const int wrd = tid % 192;    // u64 word within row

    for (int t = 0; t < T; ++t) {
        f32x4 acc = {0.f, 0.f, 0.f, 0.f};

        if (t == 0) {
            // ---- K=1536 GEMM streaming fp32 weights with inline cvt ----
            const float* qi = Wih + (size_t)(gate * H + j) * H + quad * 8;
            const float* qh = Whh + (size_t)(gate * H + j) * H + quad * 8;
            for (int kk = 0; kk < 24; ++kk) {
                short8 a_ = *(const short8*)(&lds_h[col * LDS_T0_STRIDE + kk * 32 + quad * 8]);
                short8 b_ = cvt8(qi + kk * 32);
                acc = __builtin_amdgcn_mfma_f32_16x16x32_bf16(a_, b_, acc, 0, 0, 0);
            }
            for (int kk = 0; kk < 24; ++kk) {
                short8 a_ = *(const short8*)(&lds_h[col * LDS_T0_STRIDE + (24 + kk) * 32 + quad * 8]);
                short8 b_ = cvt8(qh + kk * 32);
                acc = __builtin_amdgcn_mfma_f32_16x16x32_bf16(a_, b_, acc, 0, 0, 0);
            }
        } else {
            // ---- poll+stage h(t-1): 4 owned u64 words, BATCHED, sleepless ----
            const u64* hb = sig64c + ((size_t)(t - 1) * B + (size_t)(mtg * 16)) * 192 + wrd;
            u64 x0 = __hip_atomic_load(hb + (size_t)(r0     ) * 192,
                                       __ATOMIC_RELAXED, __HIP_MEMORY_SCOPE_AGENT);
            u64 x1 = __hip_atomic_load(hb + (size_t)(r0 +  4) * 192,
                                       __ATOMIC_RELAXED, __HIP_MEMORY_SCOPE_AGENT);
            u64 x2 = __hip_atomic_load(hb + (size_t)(r0 +  8) * 192,
                                       __ATOMIC_RELAXED, __HIP_MEMORY_SCOPE_AGENT);
            u64 x3 = __hip_atomic_load(hb + (size_t)(r0 + 12) * 192,
                                       __ATOMIC_RELAXED, __HIP_MEMORY_SCOPE_AGENT);
            unsigned pending = 0xFu;
            if (sig_ok(x0)) { *(u64*)&lds_h[(r0     ) * LDS_H_STRIDE + wrd * 4] = ~x0; pending &= ~1u; }
            if (sig_ok(x1)) { *(u64*)&lds_h[(r0 +  4) * LDS_H_STRIDE + wrd * 4] = ~x1; pending &= ~2u; }
            if (sig_ok(x2)) { *(u64*)&lds_h[(r0 +  8) * LDS_H_STRIDE + wrd * 4] = ~x2; pending &= ~4u; }
            if (sig_ok(x3)) { *(u64*)&lds_h[(r0 + 12) * LDS_H_STRIDE + wrd * 4] = ~x3; pending &= ~8u; }
            int guard = 0;
            while (pending && ++guard < (1 << 22)) {
                if (pending & 1u) x0 = __hip_atomic_load(hb + (size_t)(r0     ) * 192,
                                        __ATOMIC_RELAXED, __HIP_MEMORY_SCOPE_AGENT);
                if (pending & 2u) x1 = __hip_atomic_load(hb + (size_t)(r0 +  4) * 192,
                                        __ATOMIC_RELAXED, __HIP_MEMORY_SCOPE_AGENT);
                if (pending & 4u) x2 = __hip_atomic_load(hb + (size_t)(r0 +  8) * 192,
                                        __ATOMIC_RELAXED, __HIP_MEMORY_SCOPE_AGENT);
                if (pending & 8u) x3 = __hip_atomic_load(hb + (size_t)(r0 + 12) * 192,
                                        __ATOMIC_RELAXED, __HIP_MEMORY_SCOPE_AGENT);
                if ((pending & 1u) && sig_ok(x0)) { *(u64*)&lds_h[(r0     ) * LDS_H_STRIDE + wrd * 4] = ~x0; pending &= ~1u; }
                if ((pending & 2u) && sig_ok(x1)) { *(u64*)&lds_h[(r0 +  4) * LDS_H_STRIDE + wrd * 4] = ~x1; pending &= ~2u; }
                if ((pending & 4u) && sig_ok(x2)) { *(u64*)&lds_h[(r0 +  8) * LDS_H_STRIDE + wrd * 4] = ~x2; pending &= ~4u; }
                if ((pending & 8u) && sig_ok(x3)) { *(u64*)&lds_h[(r0 + 12) * LDS_H_STRIDE + wrd * 4] = ~x3; pending &= ~8u; }
            }
            __syncthreads();   // (B) lds_h ready

            // ---- K=768 GEMM vs pinned weights ----
            KSTEP(w00,0)  KSTEP(w01,1)  KSTEP(w02,2)  KSTEP(w03,3)
            KSTEP(w04,4)  KSTEP(w05,5)  KSTEP(w06,6)  KSTEP(w07,7)
            KSTEP(w08,8)  KSTEP(w09,9)  KSTEP(w10,10) KSTEP(w11,11)
            KSTEP(w12,12) KSTEP(w13,13) KSTEP(w14,14) KSTEP(w15,15)
            KSTEP(w16,16) KSTEP(w17,17) KSTEP(w18,18) KSTEP(w19,19)
            KSTEP(w20,20) KSTEP(w21,21) KSTEP(w22,22) KSTEP(w23,23)
        }

        // ---- exchange gate tiles through LDS ----
        float* xw = &xch[(size_t)wave * 16 * XCH_STRIDE];
#pragma unroll
        for (int r = 0; r < 4; ++r)
            xw[(quad * 4 + r) * XCH_STRIDE + col] = acc[r];
        __syncthreads();   // (C) xch ready; all lds_h reads of this step done

        // ---- cell update + inverted-bf16 publish (store IS the signal) ----
        if (p < 384) {
            const float* xg = &xch[(size_t)(cjt * 4) * 16 * XCH_STRIDE + bb * XCH_STRIDE + jcol];
            const int gs = 16 * XCH_STRIDE;
            float i0 = xg[0*gs] + bi0, i1 = xg[0*gs + 1] + bi1;
            float f0 = xg[1*gs] + bf0, f1 = xg[1*gs + 1] + bf1;
            float g0 = xg[2*gs] + bg0, g1 = xg[2*gs + 1] + bg1;
            float o0 = xg[3*gs] + bo0, o1 = xg[3*gs + 1] + bo1;
            float cn0 = sigm(f0) * c0v + sigm(i0) * tanh_fast(g0);
            float cn1 = sigm(f1) * c1v + sigm(i1) * tanh_fast(g1);
            c0v = cn0; c1v = cn1;
            __hip_bfloat16 h0b = __float2bfloat16(sigm(o0) * tanh_fast(cn0));
            __hip_bfloat16 h1b = __float2bfloat16(sigm(o1) * tanh_fast(cn1));
            unsigned lo = (unsigned)(unsigned short)~(*(unsigned short*)&h0b);  // nonzero
            unsigned hi = (unsigned)(unsigned short)~(*(unsigned short*)&h1b);  // nonzero
            __hip_atomic_store(&sig[((size_t)t * B + bglob) * 384 + (jglob >> 1)],
                               lo | (hi << 16),
                               __ATOMIC_RELAXED, __HIP_MEMORY_SCOPE_AGENT);
        }
        __syncthreads();   // (D) poll throttle: park all waves until publish done
    }
}

// ---------------- post projection (reads inverted sig) ----------------
__global__ __launch_bounds__(64) void proj(
    const short* __restrict__ Hs,            // (T*B) x 768 inverted bf16
    const __hip_bfloat16* __restrict__ Wp,   // 80 x H (padded bf16)
    const float* __restrict__ bpost,         // 72
    float* __restrict__ out)                 // B x T x 72
{
    const int mt = blockIdx.x;
    const int lane = threadIdx.x;
    const int col = lane & 15;
    const int quad = lane >> 4;

    const short* Ap = Hs + (size_t)(mt * 16 + col) * H + quad * 8;
    const short* Wb = (const short*)Wp;

    f32x4 acc[5];
#pragma unroll
    for (int nt = 0; nt < 5; ++nt) acc[nt] = (f32x4){0.f, 0.f, 0.f, 0.f};

    for (int k = 0; k < H; k += 32) {
        short8 a = ~(*(const short8*)(Ap + k));   // un-invert
#pragma unroll
        for (int nt = 0; nt < 5; ++nt) {
            short8 b = *(const short8*)(Wb + (size_t)(nt * 16 + col) * H + quad * 8 + k);
            acc[nt] = __builtin_amdgcn_mfma_f32_16x16x32_bf16(a, b, acc[nt], 0, 0, 0);
        }
    }

#pragma unroll
    for (int nt = 0; nt < 5; ++nt) {
        const int o = nt * 16 + col;
        if (o < 72) {
            const float bb = bpost[o];
#pragma unroll
            for (int r = 0; r < 4; ++r) {
                const int m = mt * 16 + quad * 4 + r;
                const int t = m >> 8;        // row = t*256 + b
                const int b = m & 255;
                out[((size_t)b * T + t) * 72 + o] = acc[nt][r] + bb;
            }
        }
    }
}

// ---------------- launch ----------------

extern "C" void kernel_launch(void* const* d_in, const int* in_sizes, int n_in,
                              void* d_out, int out_size, void* d_ws, size_t ws_size,
                              hipStream_t stream) {
    const float* src   = (const float*)d_in[0];
    const float* h0    = (const float*)d_in[2];
    const float* c0    = (const float*)d_in[3];
    const float* Wih   = (const float*)d_in[4];
    const float* Whh   = (const float*)d_in[5];
    const float* bih   = (const float*)d_in[6];
    const float* bhh   = (const float*)d_in[7];
    const float* Wpost = (const float*)d_in[8];
    const float* bpost = (const float*)d_in[9];
    float* out = (float*)d_out;

    char* ws = (char*)d_ws;
    __hip_bfloat16* Wp  = (__hip_bfloat16*)(ws + 14168064);    //    122,880 B
    unsigned*       sig = (unsigned*)(ws + 15863808);          // 39,321,600 B

    // single cooperative dispatch: in-kernel prep + grid.sync + steps 0..99
    void* args[] = { (void*)&src, (void*)&h0, (void*)&c0, (void*)&Wih, (void*)&Whh,
                     (void*)&bih, (void*)&bhh, (void*)&Wpost, (void*)&Wp, (void*)&sig };
    hipLaunchCooperativeKernel((void*)lstm_persist, dim3(256), dim3(768),
                               args, 0, stream);

    proj<<<1600, 64, 0, stream>>>((const short*)sig, Wp, bpost, out);
}

// Round 10
// 457.525 us; speedup vs baseline: 1.5156x; 1.5156x over previous
//
#include <hip/hip_runtime.h>
#include <hip/hip_bf16.h>
#include <math.h>

#define H 768
#define B 256
#define T 100

typedef __attribute__((ext_vector_type(8))) short short8;
typedef __attribute__((ext_vector_type(4))) float f32x4;
typedef __attribute__((ext_vector_type(4))) unsigned short us4;
typedef unsigned long long u64;

static __device__ __forceinline__ float sigm(float x) {
    return 1.0f / (1.0f + __expf(-x));
}
static __device__ __forceinline__ float tanh_fast(float x) {
    return 1.0f - 2.0f / (__expf(2.0f * x) + 1.0f);
}
static __device__ __forceinline__ unsigned short bf16b(float x) {
    __hip_bfloat16 h = __float2bfloat16(x);
    return *(unsigned short*)&h;
}

// ---------------- fused prep, R19 vectorized (single dispatch) ----------------
// R25 lesson (counters): do NOT move prep in-kernel. Agent-scope 8B zero
// stores have ~8x write amplification at the MALL (WRITE 38->380MB), and
// per-block fp32 weight pinning is 256x-redundant traffic (FETCH +174MB);
// lstm ballooned 337->580us. Separate prep dispatch with cached 16B stores
// is the right shape. Dispatch-merge refuted BOTH directions (R18 tail fold,
// R25 head fold).
//   bid <  2400 : sig zero   (block: 16KB via 4 x 16B stores/thread)
//   bid <  5472 : weight row y=bid-2400 (tid<192: float4 x2 loads,
//                 us4 stores to Wc + Wcat; tid==0: bias)
//   bid <  5552 : Wp row r=bid-5472 (zero-padded beyond 72)
//   bid <  5808 : A0 batch row b=bid-5552  [x0|h0]
__global__ __launch_bounds__(256) void prep_all(
        const float* __restrict__ src, const float* __restrict__ h0,
        const float* __restrict__ Wih, const float* __restrict__ Whh,
        const float* __restrict__ bih, const float* __restrict__ bhh,
        const float* __restrict__ Wpost,
        __hip_bfloat16* __restrict__ Wc,    // 3072 x 768 (Wih+Whh)
        __hip_bfloat16* __restrict__ Wcat,  // 3072 x 1536 [Wih|Whh]
        float* __restrict__ bias,           // 3072
        __hip_bfloat16* __restrict__ Wp,    // 80 x 768
        __hip_bfloat16* __restrict__ A0,    // 256 x 1536 [x0|h0]
        u64* __restrict__ sig64)            // T*B*192 u64, zeroed
{
    const int bid = blockIdx.x;
    const int tid = threadIdx.x;

    if (bid < 2400) {
        char* bz = (char*)sig64 + (size_t)bid * 16384;
        const f32x4 z = {0.f, 0.f, 0.f, 0.f};
#pragma unroll
        for (int jj = 0; jj < 4; ++jj)
            *(f32x4*)(bz + (size_t)jj * 4096 + (size_t)tid * 16) = z;
    } else if (bid < 5472) {
        const int y = bid - 2400;
        if (tid < 192) {
            const int k4 = tid * 4;
            f32x4 a = *(const f32x4*)(Wih + (size_t)y * H + k4);
            f32x4 b = *(const f32x4*)(Whh + (size_t)y * H + k4);
            us4 wc, wa, wb;
#pragma unroll
            for (int i = 0; i < 4; ++i) {
                wc[i] = bf16b(a[i] + b[i]);
                wa[i] = bf16b(a[i]);
                wb[i] = bf16b(b[i]);
            }
            unsigned short* WcS   = (unsigned short*)Wc;
            unsigned short* WcatS = (unsigned short*)Wcat;
            *(us4*)(WcS   + (size_t)y * 768  + k4)       = wc;
            *(us4*)(WcatS + (size_t)y * 1536 + k4)       = wa;
            *(us4*)(WcatS + (size_t)y * 1536 + 768 + k4) = wb;
        }
        if (tid == 0) bias[y] = bih[y] + bhh[y];
    } else if (bid < 5552) {
        const int r = bid - 5472;
        if (tid < 192) {
            const int k4 = tid * 4;
            us4 w = {0, 0, 0, 0};
            if (r < 72) {
                f32x4 v = *(const f32x4*)(Wpost + (size_t)r * H + k4);
#pragma unroll
                for (int i = 0; i < 4; ++i) w[i] = bf16b(v[i]);
            }
            *(us4*)((unsigned short*)Wp + (size_t)r * 768 + k4) = w;
        }
    } else {
        const int b = bid - 5552;
        if (tid < 192) {
            const int k4 = tid * 4;
            f32x4 s = *(const f32x4*)(src + ((size_t)b * 16 + 15) * H + k4);
            f32x4 h = *(const f32x4*)(h0  + (size_t)b * H + k4);
            us4 ws, wh;
#pragma unroll
            for (int i = 0; i < 4; ++i) { ws[i] = bf16b(s[i]); wh[i] = bf16b(h[i]); }
            unsigned short* A0S = (unsigned short*)A0;
            *(us4*)(A0S + (size_t)b * 1536 + k4)       = ws;
            *(us4*)(A0S + (size_t)b * 1536 + 768 + k4) = wh;
        }
    }
}

// ---------------- persistent recurrence: steps 0..99 ----------------
// R24 core (proven 337us: sleepless poll, full __syncthreads at (D)) with ONE
// R26 change: the retry sweep reloads ALL 4 words UNCONDITIONALLY with no
// branches between the loads, so the compiler keeps all 4 MALL round-trips
// in flight (1 RT per sweep instead of up to 4 serialized RTs behind the
// per-word `if (pending&k)` guards). Checks/stores still gated on pending.
// Refuted-by-counters (do not revisit): sc0/L2 exchange (R16); flag-gated
// exchange (R17); proj tail-fold (R18); (D)-drain removal + dual-acc MFMA
// (R22); in-kernel prep / cooperative merge (R25).
#define LDS_H_STRIDE  772    // shorts; 8B-aligned rows, low conflicts (R9-measured)
#define LDS_T0_STRIDE 1540   // shorts
#define XCH_STRIDE    17     // 16 + 1 pad floats

#define LDW8(n0,n1,n2,n3,n4,n5,n6,n7, p) \
    asm volatile("global_load_dwordx4 %0, %8, off\n\t" \
                 "global_load_dwordx4 %1, %8, off offset:64\n\t" \
                 "global_load_dwordx4 %2, %8, off offset:128\n\t" \
                 "global_load_dwordx4 %3, %8, off offset:192\n\t" \
                 "global_load_dwordx4 %4, %8, off offset:256\n\t" \
                 "global_load_dwordx4 %5, %8, off offset:320\n\t" \
                 "global_load_dwordx4 %6, %8, off offset:384\n\t" \
                 "global_load_dwordx4 %7, %8, off offset:448\n\t" \
                 "s_waitcnt vmcnt(0)" \
                 : "=&v"(n0),"=&v"(n1),"=&v"(n2),"=&v"(n3), \
                   "=&v"(n4),"=&v"(n5),"=&v"(n6),"=&v"(n7) \
                 : "v"(p))

#define KSTEP(nm, idx) { \
    short8 a_ = *(const short8*)(&lds_h[col * LDS_H_STRIDE + (idx) * 32 + quad * 8]); \
    acc = __builtin_amdgcn_mfma_f32_16x16x32_bf16(a_, nm, acc, 0, 0, 0); }

static __device__ __forceinline__ bool sig_ok(u64 x) {
    return (unsigned short)x && (unsigned short)(x >> 16) &&
           (unsigned short)(x >> 32) && (unsigned short)(x >> 48);
}

__global__ __launch_bounds__(768, 3) void lstm_persist(
    const __hip_bfloat16* __restrict__ Wc,    // 3072 x 768 bf16 (Wih+Whh)
    const __hip_bfloat16* __restrict__ Wcat,  // 3072 x 1536 bf16 [Wih|Whh]
    const float* __restrict__ bias,           // 3072
    const float* __restrict__ c0in,           // B x H fp32
    const __hip_bfloat16* __restrict__ A0,    // 256 x 1536 [x0|h0]
    unsigned* sig)                            // T x B x 384 u32 (~bf16 pairs), zeroed
{
    const int mtg  = blockIdx.x >> 4;    // batch group 0..15 (16 batches)
    const int jg   = blockIdx.x & 15;    // j group 0..15 (48 j values)
    const int tid  = threadIdx.x;
    const int lane = tid & 63;
    const int wave = tid >> 6;           // 0..11
    const int col  = lane & 15;
    const int quad = lane >> 4;
    const int jt_l = wave >> 2;          // 0..2  local j-tile
    const int gate = wave & 3;           // 0..3  (i,f,g,o)
    const int j    = jg * 48 + jt_l * 16 + col;   // this wave's j column

    __shared__ short lds_h[16 * LDS_T0_STRIDE];   // 49280 B (t0 tile; t>=1 stride 772)
    __shared__ float xch[12 * 16 * XCH_STRIDE];   // 13056 B gate exchange

    // ---- pin resident weight slice (Wc) in regs: 24 x short8 (sound asm) ----
    const short* wptr = (const short*)Wc + (size_t)(gate * H + j) * H + quad * 8;
    short8 w00,w01,w02,w03,w04,w05,w06,w07,w08,w09,w10,w11,
           w12,w13,w14,w15,w16,w17,w18,w19,w20,w21,w22,w23;
    LDW8(w00,w01,w02,w03,w04,w05,w06,w07, wptr);
    LDW8(w08,w09,w10,w11,w12,w13,w14,w15, wptr + 256);
    LDW8(w16,w17,w18,w19,w20,w21,w22,w23, wptr + 512);

    // ---- cell-role state (threads 0..383: two adjacent-j cells each) ----
    const int p    = tid;                 // pair id if < 384 (waves 0..5)
    const int bb   = p / 24;              // local batch 0..15
    const int jp   = p % 24;
    const int jloc = jp * 2;              // local j 0..46 (even)
    const int cjt  = jloc >> 4;           // j-tile of the pair
    const int jcol = jloc & 15;
    const int bglob = mtg * 16 + bb;
    const int jglob = jg * 48 + jloc;
    float c0v = 0.f, c1v = 0.f;
    float bi0=0,bi1=0,bf0=0,bf1=0,bg0=0,bg1=0,bo0=0,bo1=0;
    if (p < 384) {
        c0v = c0in[(size_t)bglob * H + jglob];
        c1v = c0in[(size_t)bglob * H + jglob + 1];
        bi0 = bias[0*H + jglob]; bi1 = bias[0*H + jglob + 1];
        bf0 = bias[1*H + jglob]; bf1 = bias[1*H + jglob + 1];
        bg0 = bias[2*H + jglob]; bg1 = bias[2*H + jglob + 1];
        bo0 = bias[3*H + jglob]; bo1 = bias[3*H + jglob + 1];
    }

    const u64* sig64c = (const u64*)sig;
    const int r0  = tid / 192;    // staging row base 0..3
    const int wrd = tid % 192;    // u64 word within row

    for (int t = 0; t < T; ++t) {
        f32x4 acc = {0.f, 0.f, 0.f, 0.f};

        if (t == 0) {
            // ---- stage A0[16 rows][1536] -> LDS (plain loads) ----
            const u64* a8 = (const u64*)((const short*)A0 + (size_t)(mtg * 16) * 1536);
#pragma unroll
            for (int i = 0; i < 8; ++i) {
                int idx = tid + i * 768;      // 0..6143 (16 rows x 384 u64)
                int br  = idx / 384;
                int ch  = idx % 384;
                *(u64*)&lds_h[br * LDS_T0_STRIDE + ch * 4] = a8[(size_t)br * 384 + ch];
            }
            __syncthreads();   // (B)

            // ---- K=1536 GEMM streaming Wcat (one-time) ----
            const short* wq = (const short*)Wcat + (size_t)(gate * H + j) * 1536 + quad * 8;
            for (int kk = 0; kk < 48; ++kk) {
                short8 a_ = *(const short8*)(&lds_h[col * LDS_T0_STRIDE + kk * 32 + quad * 8]);
                short8 b_ = *(const short8*)(wq + kk * 32);
                acc = __builtin_amdgcn_mfma_f32_16x16x32_bf16(a_, b_, acc, 0, 0, 0);
            }
        } else {
            // ---- poll+stage h(t-1): 4 owned u64 words, BATCHED loads ----
            const u64* hb = sig64c + ((size_t)(t - 1) * B + (size_t)(mtg * 16)) * 192 + wrd;
            const u64* q0 = hb + (size_t)(r0     ) * 192;
            const u64* q1 = hb + (size_t)(r0 +  4) * 192;
            const u64* q2 = hb + (size_t)(r0 +  8) * 192;
            const u64* q3 = hb + (size_t)(r0 + 12) * 192;
            u64 x0 = __hip_atomic_load(q0, __ATOMIC_RELAXED, __HIP_MEMORY_SCOPE_AGENT);
            u64 x1 = __hip_atomic_load(q1, __ATOMIC_RELAXED, __HIP_MEMORY_SCOPE_AGENT);
            u64 x2 = __hip_atomic_load(q2, __ATOMIC_RELAXED, __HIP_MEMORY_SCOPE_AGENT);
            u64 x3 = __hip_atomic_load(q3, __ATOMIC_RELAXED, __HIP_MEMORY_SCOPE_AGENT);
            unsigned pending = 0xFu;
            if (sig_ok(x0)) { *(u64*)&lds_h[(r0     ) * LDS_H_STRIDE + wrd * 4] = ~x0; pending &= ~1u; }
            if (sig_ok(x1)) { *(u64*)&lds_h[(r0 +  4) * LDS_H_STRIDE + wrd * 4] = ~x1; pending &= ~2u; }
            if (sig_ok(x2)) { *(u64*)&lds_h[(r0 +  8) * LDS_H_STRIDE + wrd * 4] = ~x2; pending &= ~4u; }
            if (sig_ok(x3)) { *(u64*)&lds_h[(r0 + 12) * LDS_H_STRIDE + wrd * 4] = ~x3; pending &= ~8u; }
            int guard = 0;
            while (pending && ++guard < (1 << 22)) {
                // R26: reload ALL 4 unconditionally, no branches between loads
                // -> all 4 MALL RTs stay in flight (1 RT per sweep).
                x0 = __hip_atomic_load(q0, __ATOMIC_RELAXED, __HIP_MEMORY_SCOPE_AGENT);
                x1 = __hip_atomic_load(q1, __ATOMIC_RELAXED, __HIP_MEMORY_SCOPE_AGENT);
                x2 = __hip_atomic_load(q2, __ATOMIC_RELAXED, __HIP_MEMORY_SCOPE_AGENT);
                x3 = __hip_atomic_load(q3, __ATOMIC_RELAXED, __HIP_MEMORY_SCOPE_AGENT);
                if ((pending & 1u) && sig_ok(x0)) { *(u64*)&lds_h[(r0     ) * LDS_H_STRIDE + wrd * 4] = ~x0; pending &= ~1u; }
                if ((pending & 2u) && sig_ok(x1)) { *(u64*)&lds_h[(r0 +  4) * LDS_H_STRIDE + wrd * 4] = ~x1; pending &= ~2u; }
                if ((pending & 4u) && sig_ok(x2)) { *(u64*)&lds_h[(r0 +  8) * LDS_H_STRIDE + wrd * 4] = ~x2; pending &= ~4u; }
                if ((pending & 8u) && sig_ok(x3)) { *(u64*)&lds_h[(r0 + 12) * LDS_H_STRIDE + wrd * 4] = ~x3; pending &= ~8u; }
            }
            __syncthreads();   // (B) lds_h ready

            // ---- K=768 GEMM vs pinned weights ----
            KSTEP(w00,0)  KSTEP(w01,1)  KSTEP(w02,2)  KSTEP(w03,3)
            KSTEP(w04,4)  KSTEP(w05,5)  KSTEP(w06,6)  KSTEP(w07,7)
            KSTEP(w08,8)  KSTEP(w09,9)  KSTEP(w10,10) KSTEP(w11,11)
            KSTEP(w12,12) KSTEP(w13,13) KSTEP(w14,14) KSTEP(w15,15)
            KSTEP(w16,16) KSTEP(w17,17) KSTEP(w18,18) KSTEP(w19,19)
            KSTEP(w20,20) KSTEP(w21,21) KSTEP(w22,22) KSTEP(w23,23)
        }

        // ---- exchange gate tiles through LDS ----
        float* xw = &xch[(size_t)wave * 16 * XCH_STRIDE];
#pragma unroll
        for (int r = 0; r < 4; ++r)
            xw[(quad * 4 + r) * XCH_STRIDE + col] = acc[r];
        __syncthreads();   // (C) xch ready; all lds_h reads of this step done

        // ---- cell update + inverted-bf16 publish (store IS the signal) ----
        if (p < 384) {
            const float* xg = &xch[(size_t)(cjt * 4) * 16 * XCH_STRIDE + bb * XCH_STRIDE + jcol];
            const int gs = 16 * XCH_STRIDE;
            float i0 = xg[0*gs] + bi0, i1 = xg[0*gs + 1] + bi1;
            float f0 = xg[1*gs] + bf0, f1 = xg[1*gs + 1] + bf1;
            float g0 = xg[2*gs] + bg0, g1 = xg[2*gs + 1] + bg1;
            float o0 = xg[3*gs] + bo0, o1 = xg[3*gs + 1] + bo1;
            float cn0 = sigm(f0) * c0v + sigm(i0) * tanh_fast(g0);
            float cn1 = sigm(f1) * c1v + sigm(i1) * tanh_fast(g1);
            c0v = cn0; c1v = cn1;
            __hip_bfloat16 h0b = __float2bfloat16(sigm(o0) * tanh_fast(cn0));
            __hip_bfloat16 h1b = __float2bfloat16(sigm(o1) * tanh_fast(cn1));
            unsigned lo = (unsigned)(unsigned short)~(*(unsigned short*)&h0b);  // nonzero
            unsigned hi = (unsigned)(unsigned short)~(*(unsigned short*)&h1b);  // nonzero
            __hip_atomic_store(&sig[((size_t)t * B + bglob) * 384 + (jglob >> 1)],
                               lo | (hi << 16),
                               __ATOMIC_RELAXED, __HIP_MEMORY_SCOPE_AGENT);
        }
        __syncthreads();   // (D) poll throttle: park all waves until publish done
    }
}

// ---------------- post projection (reads inverted sig) ----------------
__global__ __launch_bounds__(64) void proj(
    const short* __restrict__ Hs,            // (T*B) x 768 inverted bf16
    const __hip_bfloat16* __restrict__ Wp,   // 80 x H (padded bf16)
    const float* __restrict__ bpost,         // 72
    float* __restrict__ out)                 // B x T x 72
{
    const int mt = blockIdx.x;
    const int lane = threadIdx.x;
    const int col = lane & 15;
    const int quad = lane >> 4;

    const short* Ap = Hs + (size_t)(mt * 16 + col) * H + quad * 8;
    const short* Wb = (const short*)Wp;

    f32x4 acc[5];
#pragma unroll
    for (int nt = 0; nt < 5; ++nt) acc[nt] = (f32x4){0.f, 0.f, 0.f, 0.f};

    for (int k = 0; k < H; k += 32) {
        short8 a = ~(*(const short8*)(Ap + k));   // un-invert
#pragma unroll
        for (int nt = 0; nt < 5; ++nt) {
            short8 b = *(const short8*)(Wb + (size_t)(nt * 16 + col) * H + quad * 8 + k);
            acc[nt] = __builtin_amdgcn_mfma_f32_16x16x32_bf16(a, b, acc[nt], 0, 0, 0);
        }
    }

#pragma unroll
    for (int nt = 0; nt < 5; ++nt) {
        const int o = nt * 16 + col;
        if (o < 72) {
            const float bb = bpost[o];
#pragma unroll
            for (int r = 0; r < 4; ++r) {
                const int m = mt * 16 + quad * 4 + r;
                const int t = m >> 8;        // row = t*256 + b
                const int b = m & 255;
                out[((size_t)b * T + t) * 72 + o] = acc[nt][r] + bb;
            }
        }
    }
}

// ---------------- launch ----------------

extern "C" void kernel_launch(void* const* d_in, const int* in_sizes, int n_in,
                              void* d_out, int out_size, void* d_ws, size_t ws_size,
                              hipStream_t stream) {
    const float* src   = (const float*)d_in[0];
    const float* h0    = (const float*)d_in[2];
    const float* c0    = (const float*)d_in[3];
    const float* Wih   = (const float*)d_in[4];
    const float* Whh   = (const float*)d_in[5];
    const float* bih   = (const float*)d_in[6];
    const float* bhh   = (const float*)d_in[7];
    const float* Wpost = (const float*)d_in[8];
    const float* bpost = (const float*)d_in[9];
    float* out = (float*)d_out;

    char* ws = (char*)d_ws;
    __hip_bfloat16* Wcat = (__hip_bfloat16*)(ws + 0);          //  9,437,184 B
    __hip_bfloat16* Wc   = (__hip_bfloat16*)(ws + 9437184);    //  4,718,592 B
    float*          bias = (float*)(ws + 14155776);            //     12,288 B
    __hip_bfloat16* Wp   = (__hip_bfloat16*)(ws + 14168064);   //    122,880 B
    __hip_bfloat16* A0   = (__hip_bfloat16*)(ws + 14290944);   //    786,432 B
    unsigned*       sig  = (unsigned*)(ws + 15863808);         // 39,321,600 B

    // all prep (sig zero, weights, Wp, A0) in one vectorized dispatch
    prep_all<<<5808, 256, 0, stream>>>(src, h0, Wih, Whh, bih, bhh, Wpost,
                                       Wc, Wcat, bias, Wp, A0, (u64*)sig);

    // steps 0..99 in one persistent kernel (R24 core + R26 batched retry)
    lstm_persist<<<256, 768, 0, stream>>>(Wc, Wcat, bias, c0, A0, sig);

    proj<<<1600, 64, 0, stream>>>((const short*)sig, Wp, bpost, out);
}

// Round 11
// 439.284 us; speedup vs baseline: 1.5786x; 1.0415x over previous
//
#include <hip/hip_runtime.h>
#include <hip/hip_bf16.h>
#include <math.h>

#define H 768
#define B 256
#define T 100

typedef __attribute__((ext_vector_type(8))) short short8;
typedef __attribute__((ext_vector_type(4))) float f32x4;
typedef __attribute__((ext_vector_type(4))) unsigned short us4;
typedef unsigned long long u64;

static __device__ __forceinline__ float sigm(float x) {
    return 1.0f / (1.0f + __expf(-x));
}
static __device__ __forceinline__ float tanh_fast(float x) {
    return 1.0f - 2.0f / (__expf(2.0f * x) + 1.0f);
}
static __device__ __forceinline__ unsigned short bf16b(float x) {
    __hip_bfloat16 h = __float2bfloat16(x);
    return *(unsigned short*)&h;
}

// ---------------- fused prep, vectorized (single dispatch) ----------------
//   bid <  2400 : sig zero   (block: 16KB via 4 x 16B stores/thread)
//   bid <  5472 : weight row y=bid-2400 (tid<192: float4 x2 loads,
//                 us4 stores to Wc + Wcat; tid==0: bias)
//   bid <  5552 : Wp row r=bid-5472 (zero-padded beyond 72)
//   bid <  5808 : A0 batch row b=bid-5552  [x0|h0]
__global__ __launch_bounds__(256) void prep_all(
        const float* __restrict__ src, const float* __restrict__ h0,
        const float* __restrict__ Wih, const float* __restrict__ Whh,
        const float* __restrict__ bih, const float* __restrict__ bhh,
        const float* __restrict__ Wpost,
        __hip_bfloat16* __restrict__ Wc,    // 3072 x 768 (Wih+Whh)
        __hip_bfloat16* __restrict__ Wcat,  // 3072 x 1536 [Wih|Whh]
        float* __restrict__ bias,           // 3072
        __hip_bfloat16* __restrict__ Wp,    // 80 x 768
        __hip_bfloat16* __restrict__ A0,    // 256 x 1536 [x0|h0]
        u64* __restrict__ sig64)            // T*B*192 u64, zeroed
{
    const int bid = blockIdx.x;
    const int tid = threadIdx.x;

    if (bid < 2400) {
        char* bz = (char*)sig64 + (size_t)bid * 16384;
        const f32x4 z = {0.f, 0.f, 0.f, 0.f};
#pragma unroll
        for (int jj = 0; jj < 4; ++jj)
            *(f32x4*)(bz + (size_t)jj * 4096 + (size_t)tid * 16) = z;
    } else if (bid < 5472) {
        const int y = bid - 2400;
        if (tid < 192) {
            const int k4 = tid * 4;
            f32x4 a = *(const f32x4*)(Wih + (size_t)y * H + k4);
            f32x4 b = *(const f32x4*)(Whh + (size_t)y * H + k4);
            us4 wc, wa, wb;
#pragma unroll
            for (int i = 0; i < 4; ++i) {
                wc[i] = bf16b(a[i] + b[i]);
                wa[i] = bf16b(a[i]);
                wb[i] = bf16b(b[i]);
            }
            unsigned short* WcS   = (unsigned short*)Wc;
            unsigned short* WcatS = (unsigned short*)Wcat;
            *(us4*)(WcS   + (size_t)y * 768  + k4)       = wc;
            *(us4*)(WcatS + (size_t)y * 1536 + k4)       = wa;
            *(us4*)(WcatS + (size_t)y * 1536 + 768 + k4) = wb;
        }
        if (tid == 0) bias[y] = bih[y] + bhh[y];
    } else if (bid < 5552) {
        const int r = bid - 5472;
        if (tid < 192) {
            const int k4 = tid * 4;
            us4 w = {0, 0, 0, 0};
            if (r < 72) {
                f32x4 v = *(const f32x4*)(Wpost + (size_t)r * H + k4);
#pragma unroll
                for (int i = 0; i < 4; ++i) w[i] = bf16b(v[i]);
            }
            *(us4*)((unsigned short*)Wp + (size_t)r * 768 + k4) = w;
        }
    } else {
        const int b = bid - 5552;
        if (tid < 192) {
            const int k4 = tid * 4;
            f32x4 s = *(const f32x4*)(src + ((size_t)b * 16 + 15) * H + k4);
            f32x4 h = *(const f32x4*)(h0  + (size_t)b * H + k4);
            us4 ws, wh;
#pragma unroll
            for (int i = 0; i < 4; ++i) { ws[i] = bf16b(s[i]); wh[i] = bf16b(h[i]); }
            unsigned short* A0S = (unsigned short*)A0;
            *(us4*)(A0S + (size_t)b * 1536 + k4)       = ws;
            *(us4*)(A0S + (size_t)b * 1536 + 768 + k4) = wh;
        }
    }
}

// ---------------- persistent recurrence: steps 0..99 ----------------
// CONVERGED FORM (R24, proven 337us lstm / 438.5us total): R14 skeleton +
// sleepless guarded retry (R23, -16us). 256 blocks (16 mtg x 16 jg) x 768
// threads, 1 gate/wave, 24 pinned short8, batched first poll sweep, full
// __syncthreads at (D).
// Refutation ledger (all counter-evidenced; do not revisit):
//  R16 sc0/L2 exchange: agent stores bypass ALL L2s incl. producer's own;
//      sc0 polls hit stale lines forever. MALL is the only rendezvous.
//  R17 flag-gated exchange: +160us (release-flag cost + detect/transport
//      serialization + slowest-producer gating). Poll-IS-the-load wins.
//  R18 proj tail-fold: +60us (forced sc1 uncached A-reads, serializes).
//  R22 (D)-drain removal + dual-acc MFMA: null/+3.6us (wait is sweep-
//      quantized; sub-sweep shaving invisible).
//  R25 in-kernel prep + cooperative merge: +255us (8x MALL write
//      amplification on agent 8B zeroes; 256x-redundant fp32 weight reads).
//  R26 unconditional 4-word retry reload: +15us (extra load volume; guarded
//      1-load/sweep form is better).
// Residual: ~3.4us/step = producer lateness + one MALL rendezvous per step
// (intrinsic to cross-XCD recurrence on gfx950); ~100us outside lstm is
// fixed launch/teardown cost (R19/R21 bracketing).
#define LDS_H_STRIDE  772    // shorts; 8B-aligned rows, low conflicts (R9-measured)
#define LDS_T0_STRIDE 1540   // shorts
#define XCH_STRIDE    17     // 16 + 1 pad floats

#define LDW8(n0,n1,n2,n3,n4,n5,n6,n7, p) \
    asm volatile("global_load_dwordx4 %0, %8, off\n\t" \
                 "global_load_dwordx4 %1, %8, off offset:64\n\t" \
                 "global_load_dwordx4 %2, %8, off offset:128\n\t" \
                 "global_load_dwordx4 %3, %8, off offset:192\n\t" \
                 "global_load_dwordx4 %4, %8, off offset:256\n\t" \
                 "global_load_dwordx4 %5, %8, off offset:320\n\t" \
                 "global_load_dwordx4 %6, %8, off offset:384\n\t" \
                 "global_load_dwordx4 %7, %8, off offset:448\n\t" \
                 "s_waitcnt vmcnt(0)" \
                 : "=&v"(n0),"=&v"(n1),"=&v"(n2),"=&v"(n3), \
                   "=&v"(n4),"=&v"(n5),"=&v"(n6),"=&v"(n7) \
                 : "v"(p))

#define KSTEP(nm, idx) { \
    short8 a_ = *(const short8*)(&lds_h[col * LDS_H_STRIDE + (idx) * 32 + quad * 8]); \
    acc = __builtin_amdgcn_mfma_f32_16x16x32_bf16(a_, nm, acc, 0, 0, 0); }

static __device__ __forceinline__ bool sig_ok(u64 x) {
    return (unsigned short)x && (unsigned short)(x >> 16) &&
           (unsigned short)(x >> 32) && (unsigned short)(x >> 48);
}

__global__ __launch_bounds__(768, 3) void lstm_persist(
    const __hip_bfloat16* __restrict__ Wc,    // 3072 x 768 bf16 (Wih+Whh)
    const __hip_bfloat16* __restrict__ Wcat,  // 3072 x 1536 bf16 [Wih|Whh]
    const float* __restrict__ bias,           // 3072
    const float* __restrict__ c0in,           // B x H fp32
    const __hip_bfloat16* __restrict__ A0,    // 256 x 1536 [x0|h0]
    unsigned* sig)                            // T x B x 384 u32 (~bf16 pairs), zeroed
{
    const int mtg  = blockIdx.x >> 4;    // batch group 0..15 (16 batches)
    const int jg   = blockIdx.x & 15;    // j group 0..15 (48 j values)
    const int tid  = threadIdx.x;
    const int lane = tid & 63;
    const int wave = tid >> 6;           // 0..11
    const int col  = lane & 15;
    const int quad = lane >> 4;
    const int jt_l = wave >> 2;          // 0..2  local j-tile
    const int gate = wave & 3;           // 0..3  (i,f,g,o)
    const int j    = jg * 48 + jt_l * 16 + col;   // this wave's j column

    __shared__ short lds_h[16 * LDS_T0_STRIDE];   // 49280 B (t0 tile; t>=1 stride 772)
    __shared__ float xch[12 * 16 * XCH_STRIDE];   // 13056 B gate exchange

    // ---- pin resident weight slice (Wc) in regs: 24 x short8 (sound asm) ----
    const short* wptr = (const short*)Wc + (size_t)(gate * H + j) * H + quad * 8;
    short8 w00,w01,w02,w03,w04,w05,w06,w07,w08,w09,w10,w11,
           w12,w13,w14,w15,w16,w17,w18,w19,w20,w21,w22,w23;
    LDW8(w00,w01,w02,w03,w04,w05,w06,w07, wptr);
    LDW8(w08,w09,w10,w11,w12,w13,w14,w15, wptr + 256);
    LDW8(w16,w17,w18,w19,w20,w21,w22,w23, wptr + 512);

    // ---- cell-role state (threads 0..383: two adjacent-j cells each) ----
    const int p    = tid;                 // pair id if < 384 (waves 0..5)
    const int bb   = p / 24;              // local batch 0..15
    const int jp   = p % 24;
    const int jloc = jp * 2;              // local j 0..46 (even)
    const int cjt  = jloc >> 4;           // j-tile of the pair
    const int jcol = jloc & 15;
    const int bglob = mtg * 16 + bb;
    const int jglob = jg * 48 + jloc;
    float c0v = 0.f, c1v = 0.f;
    float bi0=0,bi1=0,bf0=0,bf1=0,bg0=0,bg1=0,bo0=0,bo1=0;
    if (p < 384) {
        c0v = c0in[(size_t)bglob * H + jglob];
        c1v = c0in[(size_t)bglob * H + jglob + 1];
        bi0 = bias[0*H + jglob]; bi1 = bias[0*H + jglob + 1];
        bf0 = bias[1*H + jglob]; bf1 = bias[1*H + jglob + 1];
        bg0 = bias[2*H + jglob]; bg1 = bias[2*H + jglob + 1];
        bo0 = bias[3*H + jglob]; bo1 = bias[3*H + jglob + 1];
    }

    const u64* sig64c = (const u64*)sig;
    const int r0  = tid / 192;    // staging row base 0..3
    const int wrd = tid % 192;    // u64 word within row

    for (int t = 0; t < T; ++t) {
        f32x4 acc = {0.f, 0.f, 0.f, 0.f};

        if (t == 0) {
            // ---- stage A0[16 rows][1536] -> LDS (plain loads) ----
            const u64* a8 = (const u64*)((const short*)A0 + (size_t)(mtg * 16) * 1536);
#pragma unroll
            for (int i = 0; i < 8; ++i) {
                int idx = tid + i * 768;      // 0..6143 (16 rows x 384 u64)
                int br  = idx / 384;
                int ch  = idx % 384;
                *(u64*)&lds_h[br * LDS_T0_STRIDE + ch * 4] = a8[(size_t)br * 384 + ch];
            }
            __syncthreads();   // (B)

            // ---- K=1536 GEMM streaming Wcat (one-time) ----
            const short* wq = (const short*)Wcat + (size_t)(gate * H + j) * 1536 + quad * 8;
            for (int kk = 0; kk < 48; ++kk) {
                short8 a_ = *(const short8*)(&lds_h[col * LDS_T0_STRIDE + kk * 32 + quad * 8]);
                short8 b_ = *(const short8*)(wq + kk * 32);
                acc = __builtin_amdgcn_mfma_f32_16x16x32_bf16(a_, b_, acc, 0, 0, 0);
            }
        } else {
            // ---- poll+stage h(t-1): 4 owned u64 words, BATCHED first sweep,
            //      sleepless GUARDED retries (R23/R24 proven form) ----
            const u64* hb = sig64c + ((size_t)(t - 1) * B + (size_t)(mtg * 16)) * 192 + wrd;
            u64 x0 = __hip_atomic_load(hb + (size_t)(r0     ) * 192,
                                       __ATOMIC_RELAXED, __HIP_MEMORY_SCOPE_AGENT);
            u64 x1 = __hip_atomic_load(hb + (size_t)(r0 +  4) * 192,
                                       __ATOMIC_RELAXED, __HIP_MEMORY_SCOPE_AGENT);
            u64 x2 = __hip_atomic_load(hb + (size_t)(r0 +  8) * 192,
                                       __ATOMIC_RELAXED, __HIP_MEMORY_SCOPE_AGENT);
            u64 x3 = __hip_atomic_load(hb + (size_t)(r0 + 12) * 192,
                                       __ATOMIC_RELAXED, __HIP_MEMORY_SCOPE_AGENT);
            unsigned pending = 0xFu;
            if (sig_ok(x0)) { *(u64*)&lds_h[(r0     ) * LDS_H_STRIDE + wrd * 4] = ~x0; pending &= ~1u; }
            if (sig_ok(x1)) { *(u64*)&lds_h[(r0 +  4) * LDS_H_STRIDE + wrd * 4] = ~x1; pending &= ~2u; }
            if (sig_ok(x2)) { *(u64*)&lds_h[(r0 +  8) * LDS_H_STRIDE + wrd * 4] = ~x2; pending &= ~4u; }
            if (sig_ok(x3)) { *(u64*)&lds_h[(r0 + 12) * LDS_H_STRIDE + wrd * 4] = ~x3; pending &= ~8u; }
            int guard = 0;
            while (pending && ++guard < (1 << 22)) {
                if (pending & 1u) x0 = __hip_atomic_load(hb + (size_t)(r0     ) * 192,
                                        __ATOMIC_RELAXED, __HIP_MEMORY_SCOPE_AGENT);
                if (pending & 2u) x1 = __hip_atomic_load(hb + (size_t)(r0 +  4) * 192,
                                        __ATOMIC_RELAXED, __HIP_MEMORY_SCOPE_AGENT);
                if (pending & 4u) x2 = __hip_atomic_load(hb + (size_t)(r0 +  8) * 192,
                                        __ATOMIC_RELAXED, __HIP_MEMORY_SCOPE_AGENT);
                if (pending & 8u) x3 = __hip_atomic_load(hb + (size_t)(r0 + 12) * 192,
                                        __ATOMIC_RELAXED, __HIP_MEMORY_SCOPE_AGENT);
                if ((pending & 1u) && sig_ok(x0)) { *(u64*)&lds_h[(r0     ) * LDS_H_STRIDE + wrd * 4] = ~x0; pending &= ~1u; }
                if ((pending & 2u) && sig_ok(x1)) { *(u64*)&lds_h[(r0 +  4) * LDS_H_STRIDE + wrd * 4] = ~x1; pending &= ~2u; }
                if ((pending & 4u) && sig_ok(x2)) { *(u64*)&lds_h[(r0 +  8) * LDS_H_STRIDE + wrd * 4] = ~x2; pending &= ~4u; }
                if ((pending & 8u) && sig_ok(x3)) { *(u64*)&lds_h[(r0 + 12) * LDS_H_STRIDE + wrd * 4] = ~x3; pending &= ~8u; }
            }
            __syncthreads();   // (B) lds_h ready

            // ---- K=768 GEMM vs pinned weights ----
            KSTEP(w00,0)  KSTEP(w01,1)  KSTEP(w02,2)  KSTEP(w03,3)
            KSTEP(w04,4)  KSTEP(w05,5)  KSTEP(w06,6)  KSTEP(w07,7)
            KSTEP(w08,8)  KSTEP(w09,9)  KSTEP(w10,10) KSTEP(w11,11)
            KSTEP(w12,12) KSTEP(w13,13) KSTEP(w14,14) KSTEP(w15,15)
            KSTEP(w16,16) KSTEP(w17,17) KSTEP(w18,18) KSTEP(w19,19)
            KSTEP(w20,20) KSTEP(w21,21) KSTEP(w22,22) KSTEP(w23,23)
        }

        // ---- exchange gate tiles through LDS ----
        float* xw = &xch[(size_t)wave * 16 * XCH_STRIDE];
#pragma unroll
        for (int r = 0; r < 4; ++r)
            xw[(quad * 4 + r) * XCH_STRIDE + col] = acc[r];
        __syncthreads();   // (C) xch ready; all lds_h reads of this step done

        // ---- cell update + inverted-bf16 publish (store IS the signal) ----
        if (p < 384) {
            const float* xg = &xch[(size_t)(cjt * 4) * 16 * XCH_STRIDE + bb * XCH_STRIDE + jcol];
            const int gs = 16 * XCH_STRIDE;
            float i0 = xg[0*gs] + bi0, i1 = xg[0*gs + 1] + bi1;
            float f0 = xg[1*gs] + bf0, f1 = xg[1*gs + 1] + bf1;
            float g0 = xg[2*gs] + bg0, g1 = xg[2*gs + 1] + bg1;
            float o0 = xg[3*gs] + bo0, o1 = xg[3*gs + 1] + bo1;
            float cn0 = sigm(f0) * c0v + sigm(i0) * tanh_fast(g0);
            float cn1 = sigm(f1) * c1v + sigm(i1) * tanh_fast(g1);
            c0v = cn0; c1v = cn1;
            __hip_bfloat16 h0b = __float2bfloat16(sigm(o0) * tanh_fast(cn0));
            __hip_bfloat16 h1b = __float2bfloat16(sigm(o1) * tanh_fast(cn1));
            unsigned lo = (unsigned)(unsigned short)~(*(unsigned short*)&h0b);  // nonzero
            unsigned hi = (unsigned)(unsigned short)~(*(unsigned short*)&h1b);  // nonzero
            __hip_atomic_store(&sig[((size_t)t * B + bglob) * 384 + (jglob >> 1)],
                               lo | (hi << 16),
                               __ATOMIC_RELAXED, __HIP_MEMORY_SCOPE_AGENT);
        }
        __syncthreads();   // (D) poll throttle: park all waves until publish done
    }
}

// ---------------- post projection (reads inverted sig) ----------------
__global__ __launch_bounds__(64) void proj(
    const short* __restrict__ Hs,            // (T*B) x 768 inverted bf16
    const __hip_bfloat16* __restrict__ Wp,   // 80 x H (padded bf16)
    const float* __restrict__ bpost,         // 72
    float* __restrict__ out)                 // B x T x 72
{
    const int mt = blockIdx.x;
    const int lane = threadIdx.x;
    const int col = lane & 15;
    const int quad = lane >> 4;

    const short* Ap = Hs + (size_t)(mt * 16 + col) * H + quad * 8;
    const short* Wb = (const short*)Wp;

    f32x4 acc[5];
#pragma unroll
    for (int nt = 0; nt < 5; ++nt) acc[nt] = (f32x4){0.f, 0.f, 0.f, 0.f};

    for (int k = 0; k < H; k += 32) {
        short8 a = ~(*(const short8*)(Ap + k));   // un-invert
#pragma unroll
        for (int nt = 0; nt < 5; ++nt) {
            short8 b = *(const short8*)(Wb + (size_t)(nt * 16 + col) * H + quad * 8 + k);
            acc[nt] = __builtin_amdgcn_mfma_f32_16x16x32_bf16(a, b, acc[nt], 0, 0, 0);
        }
    }

#pragma unroll
    for (int nt = 0; nt < 5; ++nt) {
        const int o = nt * 16 + col;
        if (o < 72) {
            const float bb = bpost[o];
#pragma unroll
            for (int r = 0; r < 4; ++r) {
                const int m = mt * 16 + quad * 4 + r;
                const int t = m >> 8;        // row = t*256 + b
                const int b = m & 255;
                out[((size_t)b * T + t) * 72 + o] = acc[nt][r] + bb;
            }
        }
    }
}

// ---------------- launch ----------------

extern "C" void kernel_launch(void* const* d_in, const int* in_sizes, int n_in,
                              void* d_out, int out_size, void* d_ws, size_t ws_size,
                              hipStream_t stream) {
    const float* src   = (const float*)d_in[0];
    const float* h0    = (const float*)d_in[2];
    const float* c0    = (const float*)d_in[3];
    const float* Wih   = (const float*)d_in[4];
    const float* Whh   = (const float*)d_in[5];
    const float* bih   = (const float*)d_in[6];
    const float* bhh   = (const float*)d_in[7];
    const float* Wpost = (const float*)d_in[8];
    const float* bpost = (const float*)d_in[9];
    float* out = (float*)d_out;

    char* ws = (char*)d_ws;
    __hip_bfloat16* Wcat = (__hip_bfloat16*)(ws + 0);          //  9,437,184 B
    __hip_bfloat16* Wc   = (__hip_bfloat16*)(ws + 9437184);    //  4,718,592 B
    float*          bias = (float*)(ws + 14155776);            //     12,288 B
    __hip_bfloat16* Wp   = (__hip_bfloat16*)(ws + 14168064);   //    122,880 B
    __hip_bfloat16* A0   = (__hip_bfloat16*)(ws + 14290944);   //    786,432 B
    unsigned*       sig  = (unsigned*)(ws + 15863808);         // 39,321,600 B

    // all prep (sig zero, weights, Wp, A0) in one vectorized dispatch
    prep_all<<<5808, 256, 0, stream>>>(src, h0, Wih, Whh, bih, bhh, Wpost,
                                       Wc, Wcat, bias, Wp, A0, (u64*)sig);

    // steps 0..99 in one persistent kernel (R24 converged form)
    lstm_persist<<<256, 768, 0, stream>>>(Wc, Wcat, bias, c0, A0, sig);

    proj<<<1600, 64, 0, stream>>>((const short*)sig, Wp, bpost, out);
}